// Round 1
// baseline (863.514 us; speedup 1.0000x reference)
//
#include <hip/hip_runtime.h>
#include <hip/hip_bf16.h>
#include <math.h>

#define DCH 256
#define HWD 128

typedef __attribute__((ext_vector_type(4))) float f32x4;
typedef __attribute__((ext_vector_type(8))) short s16x8;

__device__ __forceinline__ float b2f(unsigned short u) {
    union { float f; unsigned int i; } c; c.i = ((unsigned int)u) << 16; return c.f;
}
__device__ __forceinline__ unsigned short f2b(float f) {
    union { float f; unsigned int i; } c; c.f = f;
    unsigned int r = c.i + 0x7FFFu + ((c.i >> 16) & 1u);
    return (unsigned short)(r >> 16);
}

// ---------------- weight prep: fp32 -> bf16, with W1/W2 transposed ----------------
__global__ void prep_weights(const float* __restrict__ W1, const float* __restrict__ W2,
                             const float* __restrict__ Wsf, const float* __restrict__ Wsh,
                             const float* __restrict__ Wsq,
                             unsigned short* __restrict__ w1t, unsigned short* __restrict__ w2t,
                             unsigned short* __restrict__ wsf, unsigned short* __restrict__ wsh,
                             unsigned short* __restrict__ wsq)
{
    int idx = blockIdx.x * 256 + threadIdx.x;
    if (idx < 3 * 512 * 256) {               // w1t[g][n][k] = W1[g][k][n]
        int g = idx / (512 * 256); int r = idx % (512 * 256);
        int n = r / 256, k = r % 256;
        w1t[idx] = f2b(W1[((size_t)g * 256 + k) * 512 + n]);
    }
    if (idx < 3 * 256 * 256) {               // w2t[g][n][k] = W2[g][k][n]
        int g = idx / (256 * 256); int r = idx % (256 * 256);
        int n = r / 256, k = r % 256;
        w2t[idx] = f2b(W2[((size_t)g * 256 + k) * 256 + n]);
    }
    if (idx < 64 * 64) wsf[idx] = f2b(Wsf[idx]);
    if (idx < 32 * 32) wsh[idx] = f2b(Wsh[idx]);
    if (idx < 16 * 16) wsq[idx] = f2b(Wsq[idx]);
}

// ---------------- fused per-segment gMLP ----------------
// One workgroup (256 thr = 4 waves) per segment. LSEG tokens x 256 channels.
// Phases: gather+stats -> LN1 -> GEMM1(U,V)+gelu -> LN(V) -> Ws-mix+bs, *U -> GEMM2+b2 -> +res scatter
template<int LSEG, int PRr, int PCc, int GROUP>
__global__ __launch_bounds__(256, 1)
void gmlp_kernel(const float* __restrict__ x,
                 const float* __restrict__ ln1_g, const float* __restrict__ ln1_b,
                 const float* __restrict__ b1,
                 const float* __restrict__ sgu_g, const float* __restrict__ sgu_b,
                 const float* __restrict__ bs, const float* __restrict__ b2,
                 const unsigned short* __restrict__ w1t,
                 const unsigned short* __restrict__ w2t,
                 const unsigned short* __restrict__ wsp,
                 float* __restrict__ out)
{
    constexpr int TPT = 256 / LSEG;     // threads per token
    constexpr int DP  = DCH + 8;        // 264: padded bf16 stride -> 528B row, 2-way banks on b128
    constexpr int OSP = DCH + 2;        // 258: padded f32 stride for O
    constexpr int M16 = LSEG / 16;
    constexpr int SX  = LSEG * DP;

    __shared__ __align__(16) unsigned short sm_x[SX];       // residual (bf16)
    __shared__ __align__(16) unsigned short sm_y[SX];       // LN1 out; later P = u*v
    __shared__ __align__(16) unsigned short sm_uv[2 * SX];  // U | V ; later overlaid by O (f32)
    __shared__ float sm_part[2][TPT][LSEG];

    unsigned short* sm_u = sm_uv;
    unsigned short* sm_v = sm_uv + SX;
    float* sm_o = reinterpret_cast<float*>(sm_uv);          // LSEG*OSP*4 <= 2*SX*2 bytes

    int b, hr0, wr0;
    if constexpr (LSEG == 64) {                 // full windows
        b = blockIdx.x / 225; int rem = blockIdx.x % 225;
        hr0 = (rem / 15) * 8; wr0 = (rem % 15) * 8;
    } else if constexpr (LSEG == 32 && PCc == 4) {  // l / r half columns
        int side = blockIdx.x / 240; int idx = blockIdx.x % 240;
        b = idx / 15; hr0 = (idx % 15) * 8; wr0 = 120 + 4 * side;
    } else if constexpr (LSEG == 32 && PCc == 8) {  // u / d half rows
        int side = blockIdx.x / 240; int idx = blockIdx.x % 240;
        b = idx / 15; hr0 = 120 + 4 * side; wr0 = (idx % 15) * 8;
    } else {                                    // quadrants
        int quad = blockIdx.x / 16; b = blockIdx.x % 16;
        hr0 = 120 + 4 * (quad >> 1); wr0 = 120 + 4 * (quad & 1);
    }

    const int tid  = threadIdx.x;
    const int lane = tid & 63;
    const int wv   = tid >> 6;
    const int l16  = lane & 15;
    const int l4   = lane >> 4;
    const int t    = tid % LSEG;
    const int dq   = tid / LSEG;
    const int pr   = t / PCc;
    const int pc   = t % PCc;
    const int hq   = (hr0 + pr + 4) & (HWD - 1);   // rolled -> original coords
    const int wq   = (wr0 + pc + 4) & (HWD - 1);

    const size_t pix = (size_t)hq * HWD + wq;
    const float* xp = x + (size_t)b * DCH * HWD * HWD + pix;

    // ---- Phase 1: gather x (strided) + per-token stats ----
    float s1 = 0.f, s2 = 0.f;
    #pragma unroll 8
    for (int i = 0; i < DCH / TPT; ++i) {
        int d = dq + TPT * i;
        float v = xp[(size_t)d * (HWD * HWD)];
        s1 += v; s2 += v * v;
        sm_x[t * DP + d] = f2b(v);
    }
    sm_part[0][dq][t] = s1;
    sm_part[1][dq][t] = s2;
    __syncthreads();

    // ---- Phase 2: LN1 -> sm_y (bf16) ----
    {
        float mu = 0.f, sq = 0.f;
        #pragma unroll
        for (int q = 0; q < TPT; ++q) { mu += sm_part[0][q][t]; sq += sm_part[1][q][t]; }
        mu *= (1.0f / DCH);
        float var = sq * (1.0f / DCH) - mu * mu;
        float rs = rsqrtf(var + 1e-5f);
        #pragma unroll 8
        for (int i = 0; i < DCH / TPT; ++i) {
            int d = dq + TPT * i;
            float v = b2f(sm_x[t * DP + d]);
            float yv = (v - mu) * rs * ln1_g[GROUP * DCH + d] + ln1_b[GROUP * DCH + d];
            sm_y[t * DP + d] = f2b(yv);
        }
    }
    __syncthreads();

    // ---- Phase 3: GEMM1 (Y @ W1 -> gelu) two N-halves; wave wv owns cols [wv*64, wv*64+64) ----
    auto gemm1_half = [&](int nbase, unsigned short* dst) {
        f32x4 acc[M16][4];
        #pragma unroll
        for (int mi = 0; mi < M16; ++mi)
            #pragma unroll
            for (int ni = 0; ni < 4; ++ni)
                acc[mi][ni] = f32x4{0.f, 0.f, 0.f, 0.f};
        const unsigned short* wp = w1t + (size_t)GROUP * 512 * 256 + (size_t)(nbase + wv * 64) * 256;
        #pragma unroll
        for (int k0 = 0; k0 < 256; k0 += 32) {
            s16x8 a[M16], bb[4];
            #pragma unroll
            for (int mi = 0; mi < M16; ++mi)
                a[mi] = *(const s16x8*)&sm_y[(16 * mi + l16) * DP + k0 + 8 * l4];
            #pragma unroll
            for (int ni = 0; ni < 4; ++ni)
                bb[ni] = *(const s16x8*)&wp[(size_t)(16 * ni + l16) * 256 + k0 + 8 * l4];
            #pragma unroll
            for (int mi = 0; mi < M16; ++mi)
                #pragma unroll
                for (int ni = 0; ni < 4; ++ni)
                    acc[mi][ni] = __builtin_amdgcn_mfma_f32_16x16x32_bf16(a[mi], bb[ni], acc[mi][ni], 0, 0, 0);
        }
        #pragma unroll
        for (int ni = 0; ni < 4; ++ni) {
            int cu = wv * 64 + 16 * ni + l16;
            float b1v = b1[GROUP * 512 + nbase + cu];
            #pragma unroll
            for (int mi = 0; mi < M16; ++mi) {
                #pragma unroll
                for (int r = 0; r < 4; ++r) {
                    int m = 16 * mi + 4 * l4 + r;
                    float z = acc[mi][ni][r] + b1v;
                    z = 0.5f * z * (1.0f + erff(z * 0.70710678118654752f));  // exact gelu
                    dst[m * DP + cu] = f2b(z);
                }
            }
        }
    };
    gemm1_half(0, sm_u);
    gemm1_half(256, sm_v);
    __syncthreads();

    // ---- Phase 4: LN over V channels (sgu) ----
    {
        float vs1 = 0.f, vs2 = 0.f;
        #pragma unroll 8
        for (int i = 0; i < DCH / TPT; ++i) {
            int d = dq + TPT * i;
            float v = b2f(sm_v[t * DP + d]);
            vs1 += v; vs2 += v * v;
        }
        sm_part[0][dq][t] = vs1;
        sm_part[1][dq][t] = vs2;
    }
    __syncthreads();
    {
        float mu = 0.f, sq = 0.f;
        #pragma unroll
        for (int q = 0; q < TPT; ++q) { mu += sm_part[0][q][t]; sq += sm_part[1][q][t]; }
        mu *= (1.0f / DCH);
        float var = sq * (1.0f / DCH) - mu * mu;
        float rs = rsqrtf(var + 1e-5f);
        #pragma unroll 8
        for (int i = 0; i < DCH / TPT; ++i) {
            int d = dq + TPT * i;
            float v = b2f(sm_v[t * DP + d]);
            sm_v[t * DP + d] = f2b((v - mu) * rs * sgu_g[GROUP * DCH + d] + sgu_b[GROUP * DCH + d]);
        }
    }
    __syncthreads();

    // ---- Phase 5: token-mix  P = U .* (Ws @ V + bs)  -> sm_y ----
    {
        f32x4 acc[M16][4];
        #pragma unroll
        for (int mi = 0; mi < M16; ++mi)
            #pragma unroll
            for (int ni = 0; ni < 4; ++ni)
                acc[mi][ni] = f32x4{0.f, 0.f, 0.f, 0.f};
        constexpr int KS = (LSEG + 31) / 32;    // k-steps (LSEG=16 zero-padded to 32)
        #pragma unroll
        for (int ks = 0; ks < KS; ++ks) {
            const int k0 = ks * 32;
            s16x8 a[M16], bb[4];
            #pragma unroll
            for (int mi = 0; mi < M16; ++mi) {
                if constexpr (LSEG == 16) {
                    s16x8 av = {0,0,0,0,0,0,0,0};
                    if (l4 < 2) av = *(const s16x8*)&wsp[(16 * mi + l16) * LSEG + 8 * l4];
                    a[mi] = av;
                } else {
                    a[mi] = *(const s16x8*)&wsp[(16 * mi + l16) * LSEG + k0 + 8 * l4];
                }
            }
            #pragma unroll
            for (int ni = 0; ni < 4; ++ni) {
                int cv = wv * 64 + 16 * ni + l16;
                s16x8 bv;
                #pragma unroll
                for (int j = 0; j < 8; ++j) {
                    int k = k0 + 8 * l4 + j;
                    short val = 0;
                    if (LSEG >= 32 || l4 < 2) val = (short)sm_v[k * DP + cv];  // column read of V
                    bv[j] = val;
                }
                bb[ni] = bv;
            }
            #pragma unroll
            for (int mi = 0; mi < M16; ++mi)
                #pragma unroll
                for (int ni = 0; ni < 4; ++ni)
                    acc[mi][ni] = __builtin_amdgcn_mfma_f32_16x16x32_bf16(a[mi], bb[ni], acc[mi][ni], 0, 0, 0);
        }
        #pragma unroll
        for (int ni = 0; ni < 4; ++ni) {
            int cv = wv * 64 + 16 * ni + l16;
            #pragma unroll
            for (int mi = 0; mi < M16; ++mi) {
                #pragma unroll
                for (int r = 0; r < 4; ++r) {
                    int m = 16 * mi + 4 * l4 + r;
                    float vm = acc[mi][ni][r] + bs[m];
                    float p = vm * b2f(sm_u[m * DP + cv]);
                    sm_y[m * DP + cv] = f2b(p);
                }
            }
        }
    }
    __syncthreads();

    // ---- Phase 6: GEMM2  O = P @ W2 + b2  -> sm_o (f32, overlays U/V) ----
    {
        f32x4 acc[M16][4];
        #pragma unroll
        for (int mi = 0; mi < M16; ++mi)
            #pragma unroll
            for (int ni = 0; ni < 4; ++ni)
                acc[mi][ni] = f32x4{0.f, 0.f, 0.f, 0.f};
        const unsigned short* wp = w2t + (size_t)GROUP * 256 * 256 + (size_t)(wv * 64) * 256;
        #pragma unroll
        for (int k0 = 0; k0 < 256; k0 += 32) {
            s16x8 a[M16], bb[4];
            #pragma unroll
            for (int mi = 0; mi < M16; ++mi)
                a[mi] = *(const s16x8*)&sm_y[(16 * mi + l16) * DP + k0 + 8 * l4];
            #pragma unroll
            for (int ni = 0; ni < 4; ++ni)
                bb[ni] = *(const s16x8*)&wp[(size_t)(16 * ni + l16) * 256 + k0 + 8 * l4];
            #pragma unroll
            for (int mi = 0; mi < M16; ++mi)
                #pragma unroll
                for (int ni = 0; ni < 4; ++ni)
                    acc[mi][ni] = __builtin_amdgcn_mfma_f32_16x16x32_bf16(a[mi], bb[ni], acc[mi][ni], 0, 0, 0);
        }
        #pragma unroll
        for (int ni = 0; ni < 4; ++ni) {
            int cu = wv * 64 + 16 * ni + l16;
            float b2v = b2[GROUP * DCH + cu];
            #pragma unroll
            for (int mi = 0; mi < M16; ++mi) {
                #pragma unroll
                for (int r = 0; r < 4; ++r) {
                    int m = 16 * mi + 4 * l4 + r;
                    sm_o[m * OSP + cu] = acc[mi][ni][r] + b2v;
                }
            }
        }
    }
    __syncthreads();

    // ---- Phase 7: residual add + scatter back to original coords ----
    {
        float* op = out + (size_t)b * DCH * HWD * HWD + pix;
        #pragma unroll 8
        for (int i = 0; i < DCH / TPT; ++i) {
            int d = dq + TPT * i;
            float v = sm_o[t * OSP + d] + b2f(sm_x[t * DP + d]);
            op[(size_t)d * (HWD * HWD)] = v;
        }
    }
}

extern "C" void kernel_launch(void* const* d_in, const int* in_sizes, int n_in,
                              void* d_out, int out_size, void* d_ws, size_t ws_size,
                              hipStream_t stream)
{
    (void)in_sizes; (void)n_in; (void)out_size; (void)ws_size;
    const float* x     = (const float*)d_in[0];
    const float* ln1_g = (const float*)d_in[1];
    const float* ln1_b = (const float*)d_in[2];
    const float* W1    = (const float*)d_in[3];
    const float* b1    = (const float*)d_in[4];
    const float* sgu_g = (const float*)d_in[5];
    const float* sgu_b = (const float*)d_in[6];
    const float* Wsf   = (const float*)d_in[7];
    const float* bsf   = (const float*)d_in[8];
    const float* Wsh   = (const float*)d_in[9];
    const float* bsh   = (const float*)d_in[10];
    const float* Wsq   = (const float*)d_in[11];
    const float* bsq   = (const float*)d_in[12];
    const float* W2    = (const float*)d_in[13];
    const float* b2    = (const float*)d_in[14];
    float* out = (float*)d_out;

    unsigned short* w1t = (unsigned short*)d_ws;       // 3*512*256 bf16
    unsigned short* w2t = w1t + 3 * 512 * 256;         // 3*256*256 bf16
    unsigned short* wsf = w2t + 3 * 256 * 256;         // 64*64
    unsigned short* wsh = wsf + 64 * 64;               // 32*32
    unsigned short* wsq = wsh + 32 * 32;               // 16*16

    hipLaunchKernelGGL(prep_weights, dim3(1536), dim3(256), 0, stream,
                       W1, W2, Wsf, Wsh, Wsq, w1t, w2t, wsf, wsh, wsq);

    hipLaunchKernelGGL((gmlp_kernel<64, 8, 8, 0>), dim3(3600), dim3(256), 0, stream,
                       x, ln1_g, ln1_b, b1, sgu_g, sgu_b, bsf, b2, w1t, w2t, wsf, out);
    hipLaunchKernelGGL((gmlp_kernel<32, 8, 4, 1>), dim3(480), dim3(256), 0, stream,
                       x, ln1_g, ln1_b, b1, sgu_g, sgu_b, bsh, b2, w1t, w2t, wsh, out);
    hipLaunchKernelGGL((gmlp_kernel<32, 4, 8, 1>), dim3(480), dim3(256), 0, stream,
                       x, ln1_g, ln1_b, b1, sgu_g, sgu_b, bsh, b2, w1t, w2t, wsh, out);
    hipLaunchKernelGGL((gmlp_kernel<16, 4, 4, 2>), dim3(64), dim3(256), 0, stream,
                       x, ln1_g, ln1_b, b1, sgu_g, sgu_b, bsq, b2, w1t, w2t, wsq, out);
}

// Round 2
// 631.493 us; speedup vs baseline: 1.3674x; 1.3674x over previous
//
#include <hip/hip_runtime.h>
#include <hip/hip_bf16.h>
#include <math.h>

#define DCH 256
#define HWD 128

typedef __attribute__((ext_vector_type(4))) float f32x4;
typedef __attribute__((ext_vector_type(8))) short s16x8;
typedef __attribute__((ext_vector_type(4))) short s16x4;

__device__ __forceinline__ float b2f(unsigned short u) {
    union { float f; unsigned int i; } c; c.i = ((unsigned int)u) << 16; return c.f;
}
__device__ __forceinline__ unsigned short f2b(float f) {
    union { float f; unsigned int i; } c; c.f = f;
    unsigned int r = c.i + 0x7FFFu + ((c.i >> 16) & 1u);
    return (unsigned short)(r >> 16);
}

// ---------------- weight prep: fp32 -> bf16, with W1/W2 transposed ----------------
__global__ void prep_weights(const float* __restrict__ W1, const float* __restrict__ W2,
                             const float* __restrict__ Wsf, const float* __restrict__ Wsh,
                             const float* __restrict__ Wsq,
                             unsigned short* __restrict__ w1t, unsigned short* __restrict__ w2t,
                             unsigned short* __restrict__ wsf, unsigned short* __restrict__ wsh,
                             unsigned short* __restrict__ wsq)
{
    int idx = blockIdx.x * 256 + threadIdx.x;
    if (idx < 3 * 512 * 256) {               // w1t[g][n][k] = W1[g][k][n]
        int g = idx / (512 * 256); int r = idx % (512 * 256);
        int n = r / 256, k = r % 256;
        w1t[idx] = f2b(W1[((size_t)g * 256 + k) * 512 + n]);
    }
    if (idx < 3 * 256 * 256) {               // w2t[g][n][k] = W2[g][k][n]
        int g = idx / (256 * 256); int r = idx % (256 * 256);
        int n = r / 256, k = r % 256;
        w2t[idx] = f2b(W2[((size_t)g * 256 + k) * 256 + n]);
    }
    if (idx < 64 * 64) wsf[idx] = f2b(Wsf[idx]);
    if (idx < 32 * 32) wsh[idx] = f2b(Wsh[idx]);
    if (idx < 16 * 16) wsq[idx] = f2b(Wsq[idx]);
}

// ---------------- fused per-segment gMLP, 1024 threads (16 waves) per segment ----------------
// LDS regions: A: Y -> Vt -> (O with B)   B: U -> (O)   C: V -> P   D: residual x   E: stats
template<int LSEG, int GROUP>
__global__ __launch_bounds__(1024, 1)
void gmlp_kernel(const float* __restrict__ x,
                 const float* __restrict__ ln1_g, const float* __restrict__ ln1_b,
                 const float* __restrict__ b1,
                 const float* __restrict__ sgu_g, const float* __restrict__ sgu_b,
                 const float* __restrict__ bs, const float* __restrict__ b2,
                 const unsigned short* __restrict__ w1t,
                 const unsigned short* __restrict__ w2t,
                 const unsigned short* __restrict__ wsp,
                 float* __restrict__ out)
{
    constexpr int TPT = 1024 / LSEG;          // threads per token
    constexpr int CPT = DCH / TPT;            // channels per thread (contiguous chunk)
    constexpr int DP  = DCH + 8;              // 264 bf16 stride (row = 528B)
    constexpr int OSP = DCH + 4;              // 260 f32 stride (row = 1040B, 16B-aligned)
    constexpr int M16 = LSEG / 16;
    constexpr int VTP = (LSEG == 64) ? 72 : (LSEG == 32 ? 40 : 24);  // Vt stride (16B-aligned rows)
    constexpr int SZY = LSEG * DP * 2;
    constexpr int SZVT = 256 * VTP * 2;
    constexpr int SZA = (SZVT > SZY) ? SZVT : SZY;
    constexpr int SMTOT = SZA + 3 * SZY + 2 * 1024 * 4;
    static_assert(SZA + SZY >= LSEG * OSP * 4, "O must fit in A+B");

    __shared__ __align__(16) unsigned char smem[SMTOT];
    unsigned short* sm_y  = (unsigned short*)smem;                 // Y (LN1 out)
    unsigned short* sm_vt = (unsigned short*)smem;                 // Vt[ch][token] (after GEMM1)
    float*          sm_o  = (float*)smem;                          // O (phase 6+, overlays A+B)
    unsigned short* sm_u  = (unsigned short*)(smem + SZA);         // U
    unsigned short* sm_v  = (unsigned short*)(smem + SZA + SZY);   // V, then P
    unsigned short* sm_x  = (unsigned short*)(smem + SZA + 2*SZY); // residual (bf16)
    float*          sm_part = (float*)(smem + SZA + 3*SZY);        // [2][TPT][LSEG]

    const int tid  = threadIdx.x;
    const int lane = tid & 63;
    const int wv   = tid >> 6;                // 0..15
    const int l16  = lane & 15;
    const int l4   = lane >> 4;
    const int t    = tid & (LSEG - 1);
    const int dq   = tid / LSEG;
    const int d0   = dq * CPT;

    int b, hr0, wr0, pr, pc;
    if constexpr (LSEG == 64) {
        b = blockIdx.x / 225; int rem = blockIdx.x % 225;
        hr0 = (rem / 15) * 8; wr0 = (rem % 15) * 8;
        pr = t >> 3; pc = t & 7;
    } else if constexpr (LSEG == 32) {
        int ix = blockIdx.x;
        if (ix < 480) {                       // l / r vertical strips (8 rows x 4 cols)
            int side = ix / 240; int j = ix % 240;
            b = j / 15; hr0 = (j % 15) * 8; wr0 = 120 + 4 * side;
            pr = t >> 2; pc = t & 3;
        } else {                              // u / d horizontal strips (4 rows x 8 cols)
            ix -= 480; int side = ix / 240; int j = ix % 240;
            b = j / 15; hr0 = 120 + 4 * side; wr0 = (j % 15) * 8;
            pr = t >> 3; pc = t & 7;
        }
    } else {                                  // quadrants 4x4
        int quad = blockIdx.x >> 4; b = blockIdx.x & 15;
        hr0 = 120 + 4 * (quad >> 1); wr0 = 120 + 4 * (quad & 1);
        pr = t >> 2; pc = t & 3;
    }

    const int hq = (hr0 + pr + 4) & (HWD - 1);
    const int wq = (wr0 + pc + 4) & (HWD - 1);
    const size_t plane = (size_t)HWD * HWD;
    const size_t pix = (size_t)hq * HWD + wq;
    const float* xp = x + (size_t)b * DCH * plane + pix;

    // ---- Phase 1: gather x (coalesced within wave) + per-token partial stats ----
    {
        float s1 = 0.f, s2 = 0.f;
        float vals[CPT];
        #pragma unroll
        for (int i = 0; i < CPT; ++i) {
            float v = xp[(size_t)(d0 + i) * plane];
            vals[i] = v; s1 += v; s2 += v * v;
        }
        #pragma unroll
        for (int i = 0; i < CPT; i += 4) {
            s16x4 pk;
            #pragma unroll
            for (int j = 0; j < 4; ++j) pk[j] = (short)f2b(vals[i + j]);
            *(s16x4*)&sm_x[t * DP + d0 + i] = pk;
        }
        sm_part[(0 * TPT + dq) * LSEG + t] = s1;
        sm_part[(1 * TPT + dq) * LSEG + t] = s2;
    }
    __syncthreads();

    // ---- Phase 2: LN1 -> sm_y ----
    {
        float mu = 0.f, sq = 0.f;
        #pragma unroll
        for (int q = 0; q < TPT; ++q) {
            mu += sm_part[(0 * TPT + q) * LSEG + t];
            sq += sm_part[(1 * TPT + q) * LSEG + t];
        }
        mu *= (1.0f / DCH);
        float var = sq * (1.0f / DCH) - mu * mu;
        float rs = rsqrtf(var + 1e-5f);
        #pragma unroll
        for (int i = 0; i < CPT; i += 4) {
            s16x4 xv = *(s16x4*)&sm_x[t * DP + d0 + i];
            f32x4 g = *(const f32x4*)&ln1_g[GROUP * DCH + d0 + i];
            f32x4 bv = *(const f32x4*)&ln1_b[GROUP * DCH + d0 + i];
            s16x4 yv;
            #pragma unroll
            for (int j = 0; j < 4; ++j)
                yv[j] = (short)f2b((b2f((unsigned short)xv[j]) - mu) * rs * g[j] + bv[j]);
            *(s16x4*)&sm_y[t * DP + d0 + i] = yv;
        }
    }
    __syncthreads();

    // ---- Phase 3: GEMM1  [LSEG x 256] @ [256 x 512] -> gelu -> U | V ; wave owns 32 cols ----
    {
        f32x4 acc[M16][2];
        #pragma unroll
        for (int mi = 0; mi < M16; ++mi)
            #pragma unroll
            for (int ni = 0; ni < 2; ++ni)
                acc[mi][ni] = f32x4{0.f, 0.f, 0.f, 0.f};
        const unsigned short* wp = w1t + (size_t)GROUP * 512 * 256 + (size_t)(wv * 32) * 256;
        #pragma unroll
        for (int k0 = 0; k0 < 256; k0 += 32) {
            s16x8 a[M16], bb[2];
            #pragma unroll
            for (int mi = 0; mi < M16; ++mi)
                a[mi] = *(const s16x8*)&sm_y[(16 * mi + l16) * DP + k0 + 8 * l4];
            #pragma unroll
            for (int ni = 0; ni < 2; ++ni)
                bb[ni] = *(const s16x8*)&wp[(size_t)(16 * ni + l16) * 256 + k0 + 8 * l4];
            #pragma unroll
            for (int mi = 0; mi < M16; ++mi)
                #pragma unroll
                for (int ni = 0; ni < 2; ++ni)
                    acc[mi][ni] = __builtin_amdgcn_mfma_f32_16x16x32_bf16(a[mi], bb[ni], acc[mi][ni], 0, 0, 0);
        }
        #pragma unroll
        for (int ni = 0; ni < 2; ++ni) {
            int ncol = wv * 32 + 16 * ni + l16;
            float b1v = b1[GROUP * 512 + ncol];
            unsigned short* dst = (ncol < 256) ? (sm_u + ncol) : (sm_v + (ncol - 256));
            #pragma unroll
            for (int mi = 0; mi < M16; ++mi) {
                #pragma unroll
                for (int r = 0; r < 4; ++r) {
                    int m = 16 * mi + 4 * l4 + r;
                    float z = acc[mi][ni][r] + b1v;
                    z = 0.5f * z * (1.0f + erff(z * 0.70710678118654752f));
                    dst[m * DP] = f2b(z);
                }
            }
        }
    }
    __syncthreads();

    // ---- Phase 4: LN over V channels; write TRANSPOSED Vt[ch][token] (overlays Y) ----
    {
        float s1 = 0.f, s2 = 0.f;
        #pragma unroll
        for (int i = 0; i < CPT; i += 4) {
            s16x4 vv = *(s16x4*)&sm_v[t * DP + d0 + i];
            #pragma unroll
            for (int j = 0; j < 4; ++j) { float f = b2f((unsigned short)vv[j]); s1 += f; s2 += f * f; }
        }
        sm_part[(0 * TPT + dq) * LSEG + t] = s1;
        sm_part[(1 * TPT + dq) * LSEG + t] = s2;
    }
    __syncthreads();
    {
        float mu = 0.f, sq = 0.f;
        #pragma unroll
        for (int q = 0; q < TPT; ++q) {
            mu += sm_part[(0 * TPT + q) * LSEG + t];
            sq += sm_part[(1 * TPT + q) * LSEG + t];
        }
        mu *= (1.0f / DCH);
        float var = sq * (1.0f / DCH) - mu * mu;
        float rs = rsqrtf(var + 1e-5f);
        #pragma unroll
        for (int i = 0; i < CPT; i += 4) {
            s16x4 vv = *(s16x4*)&sm_v[t * DP + d0 + i];
            f32x4 g = *(const f32x4*)&sgu_g[GROUP * DCH + d0 + i];
            f32x4 bv = *(const f32x4*)&sgu_b[GROUP * DCH + d0 + i];
            #pragma unroll
            for (int j = 0; j < 4; ++j)
                sm_vt[(d0 + i + j) * VTP + t] =
                    f2b((b2f((unsigned short)vv[j]) - mu) * rs * g[j] + bv[j]);
        }
    }
    __syncthreads();

    // ---- Phase 5: token-mix  P = U .* (Ws @ V + bs)  -> P over sm_v ; wave owns 16 cols ----
    {
        f32x4 acc[M16];
        #pragma unroll
        for (int mi = 0; mi < M16; ++mi) acc[mi] = f32x4{0.f, 0.f, 0.f, 0.f};
        const int cv = wv * 16 + l16;
        constexpr int KS = (LSEG >= 32) ? (LSEG / 32) : 1;
        #pragma unroll
        for (int ks = 0; ks < KS; ++ks) {
            const int k0 = 32 * ks;
            s16x8 a[M16], bv;
            if constexpr (LSEG == 16) {
                s16x8 z8 = {0,0,0,0,0,0,0,0};
                a[0] = (l4 < 2) ? *(const s16x8*)&wsp[l16 * 16 + 8 * l4] : z8;
                bv   = (l4 < 2) ? *(const s16x8*)&sm_vt[cv * VTP + 8 * l4] : z8;
            } else {
                #pragma unroll
                for (int mi = 0; mi < M16; ++mi)
                    a[mi] = *(const s16x8*)&wsp[(16 * mi + l16) * LSEG + k0 + 8 * l4];
                bv = *(const s16x8*)&sm_vt[cv * VTP + k0 + 8 * l4];
            }
            #pragma unroll
            for (int mi = 0; mi < M16; ++mi)
                acc[mi] = __builtin_amdgcn_mfma_f32_16x16x32_bf16(a[mi], bv, acc[mi], 0, 0, 0);
        }
        #pragma unroll
        for (int mi = 0; mi < M16; ++mi) {
            #pragma unroll
            for (int r = 0; r < 4; ++r) {
                int m = 16 * mi + 4 * l4 + r;
                float vm = acc[mi][r] + bs[m];
                float p = vm * b2f(sm_u[m * DP + cv]);
                sm_v[m * DP + cv] = f2b(p);
            }
        }
    }
    __syncthreads();

    // ---- Phase 6: GEMM2  O = P @ W2 + b2 -> sm_o (f32, overlays A+B) ; wave owns 16 cols ----
    {
        f32x4 acc[M16];
        #pragma unroll
        for (int mi = 0; mi < M16; ++mi) acc[mi] = f32x4{0.f, 0.f, 0.f, 0.f};
        const unsigned short* wp2 = w2t + (size_t)GROUP * 256 * 256 + (size_t)(wv * 16) * 256;
        #pragma unroll
        for (int k0 = 0; k0 < 256; k0 += 32) {
            s16x8 a[M16], bb;
            #pragma unroll
            for (int mi = 0; mi < M16; ++mi)
                a[mi] = *(const s16x8*)&sm_v[(16 * mi + l16) * DP + k0 + 8 * l4];
            bb = *(const s16x8*)&wp2[(size_t)l16 * 256 + k0 + 8 * l4];
            #pragma unroll
            for (int mi = 0; mi < M16; ++mi)
                acc[mi] = __builtin_amdgcn_mfma_f32_16x16x32_bf16(a[mi], bb, acc[mi], 0, 0, 0);
        }
        const int cu = wv * 16 + l16;
        float b2v = b2[GROUP * DCH + cu];
        #pragma unroll
        for (int mi = 0; mi < M16; ++mi) {
            #pragma unroll
            for (int r = 0; r < 4; ++r) {
                int m = 16 * mi + 4 * l4 + r;
                sm_o[m * OSP + cu] = acc[mi][r] + b2v;
            }
        }
    }
    __syncthreads();

    // ---- Phase 7: residual add + coalesced scatter ----
    {
        float* op = out + (size_t)b * DCH * plane + pix;
        #pragma unroll
        for (int i = 0; i < CPT; i += 4) {
            f32x4 ov = *(f32x4*)&sm_o[t * OSP + d0 + i];
            s16x4 xv = *(s16x4*)&sm_x[t * DP + d0 + i];
            #pragma unroll
            for (int j = 0; j < 4; ++j)
                op[(size_t)(d0 + i + j) * plane] = ov[j] + b2f((unsigned short)xv[j]);
        }
    }
}

extern "C" void kernel_launch(void* const* d_in, const int* in_sizes, int n_in,
                              void* d_out, int out_size, void* d_ws, size_t ws_size,
                              hipStream_t stream)
{
    (void)in_sizes; (void)n_in; (void)out_size; (void)ws_size;
    const float* x     = (const float*)d_in[0];
    const float* ln1_g = (const float*)d_in[1];
    const float* ln1_b = (const float*)d_in[2];
    const float* W1    = (const float*)d_in[3];
    const float* b1    = (const float*)d_in[4];
    const float* sgu_g = (const float*)d_in[5];
    const float* sgu_b = (const float*)d_in[6];
    const float* Wsf   = (const float*)d_in[7];
    const float* bsf   = (const float*)d_in[8];
    const float* Wsh   = (const float*)d_in[9];
    const float* bsh   = (const float*)d_in[10];
    const float* Wsq   = (const float*)d_in[11];
    const float* bsq   = (const float*)d_in[12];
    const float* W2    = (const float*)d_in[13];
    const float* b2    = (const float*)d_in[14];
    float* out = (float*)d_out;

    unsigned short* w1t = (unsigned short*)d_ws;       // 3*512*256 bf16
    unsigned short* w2t = w1t + 3 * 512 * 256;         // 3*256*256 bf16
    unsigned short* wsf = w2t + 3 * 256 * 256;         // 64*64
    unsigned short* wsh = wsf + 64 * 64;               // 32*32
    unsigned short* wsq = wsh + 32 * 32;               // 16*16

    hipLaunchKernelGGL(prep_weights, dim3(1536), dim3(256), 0, stream,
                       W1, W2, Wsf, Wsh, Wsq, w1t, w2t, wsf, wsh, wsq);

    hipLaunchKernelGGL((gmlp_kernel<64, 0>), dim3(3600), dim3(1024), 0, stream,
                       x, ln1_g, ln1_b, b1, sgu_g, sgu_b, bsf, b2, w1t, w2t, wsf, out);
    hipLaunchKernelGGL((gmlp_kernel<32, 1>), dim3(960), dim3(1024), 0, stream,
                       x, ln1_g, ln1_b, b1, sgu_g, sgu_b, bsh, b2, w1t, w2t, wsh, out);
    hipLaunchKernelGGL((gmlp_kernel<16, 2>), dim3(64), dim3(1024), 0, stream,
                       x, ln1_g, ln1_b, b1, sgu_g, sgu_b, bsq, b2, w1t, w2t, wsq, out);
}